// Round 16
// baseline (242.125 us; speedup 1.0000x reference)
//
#include <hip/hip_runtime.h>
#include <math.h>

#define BN 64
#define PN 16800
#define ON 64
#define THRESH 0.35f
#define NEGPOS 7
#define GXB 17                 // best_truth blocks per row (1024 priors/block, 4/thread)
#define NBT (BN * GXB)         // 1088 bt blocks
#define PT 4                   // priors per thread in best_truth
#define TG 4                   // truths per block in best_prior
#define PSPLIT 2               // bp priors split
#define PHALF 8400
#define NBP2 (BN * 16 * PSPLIT) // 2048 bp blocks
#define NBINS 4096
#define MAXM 4096
#define TAILT 104              // threads with tail work in select (416/4)
#define BMW 525                // bitmap words (16800/32)

struct GAcc {
  unsigned ticket;
  float sl, slm, sc;
  int np, np1;
  unsigned pad0, pad1;
};

__device__ __forceinline__ unsigned f2key(float f) {
  unsigned u = __float_as_uint(f);
  return (u & 0x80000000u) ? ~u : (u | 0x80000000u);
}
__device__ __forceinline__ float key2f(unsigned k) {
  unsigned u = (k & 0x80000000u) ? (k & 0x7FFFFFFFu) : ~k;
  return __uint_as_float(u);
}
__device__ __forceinline__ float sl1(float d) {
  float a = fabsf(d);
  return (a < 1.f) ? 0.5f * a * a : a - 0.5f;
}

// ====== K1: combined grid — best_truth blocks + split best_prior blocks (R14) ======
__global__ void k_match2(const float* __restrict__ priors,
                         const float* __restrict__ targets,
                         float* __restrict__ bto, int* __restrict__ bti,
                         unsigned long long* __restrict__ bpp,
                         GAcc* __restrict__ gacc) {
  int bid = blockIdx.x;
  int tid = threadIdx.x;

  if (bid < NBT) {
    int b = bid / GXB;
    int slab = bid - b * GXB;
    int base = slab * 1024 + tid;
    if (bid == 0 && tid < 8) ((unsigned*)gacc)[tid] = 0;

    __shared__ float4 tbox[ON];
    __shared__ float tarea[ON];
    if (tid < ON) {
      const float* tg = &targets[((long)b * ON + tid) * 15];
      float4 bx = make_float4(tg[0], tg[1], tg[2], tg[3]);
      tbox[tid] = bx;
      tarea[tid] = (bx.z - bx.x) * (bx.w - bx.y);
    }
    __syncthreads();

    float px1[PT], py1[PT], px2[PT], py2[PT], ab[PT];
    bool val[PT];
#pragma unroll
    for (int i = 0; i < PT; i++) {
      int p = base + 256 * i;
      val[i] = p < PN;
      float4 pr = reinterpret_cast<const float4*>(priors)[val[i] ? p : base];
      px1[i] = pr.x - pr.z * 0.5f; py1[i] = pr.y - pr.w * 0.5f;
      px2[i] = pr.x + pr.z * 0.5f; py2[i] = pr.y + pr.w * 0.5f;
      ab[i] = (px2[i] - px1[i]) * (py2[i] - py1[i]);
    }
    float bi[PT], bu[PT]; int id[PT];
#pragma unroll
    for (int i = 0; i < PT; i++) { bi[i] = -1.f; bu[i] = 1.f; id[i] = 0; }

#pragma unroll 4
    for (int t = 0; t < ON; t++) {
      float4 a = tbox[t];
      float aa = tarea[t];
#pragma unroll
      for (int i = 0; i < PT; i++) {
        float lx = fmaxf(a.x, px1[i]), ly = fmaxf(a.y, py1[i]);
        float rx = fminf(a.z, px2[i]), ry = fminf(a.w, py2[i]);
        float w = fmaxf(rx - lx, 0.f), h = fmaxf(ry - ly, 0.f);
        float inter = w * h;
        float uni = aa + ab[i] - inter;
        if (inter * bu[i] > bi[i] * uni) { bi[i] = inter; bu[i] = uni; id[i] = t; }
      }
    }
#pragma unroll
    for (int i = 0; i < PT; i++) {
      if (val[i]) {
        int p = base + 256 * i;
        bto[(long)b * PN + p] = bi[i] / bu[i];
        bti[(long)b * PN + p] = id[i];
      }
    }
  } else {
    int id2 = bid - NBT;
    int b = id2 >> 5;
    int rest = id2 & 31;
    int g = rest >> 1;
    int h = rest & 1;
    int t0 = g * TG;
    float ax1[TG], ay1[TG], ax2[TG], ay2[TG], area_a[TG];
#pragma unroll
    for (int i = 0; i < TG; i++) {
      const float* tg = &targets[((long)b * ON + t0 + i) * 15];
      ax1[i] = tg[0]; ay1[i] = tg[1]; ax2[i] = tg[2]; ay2[i] = tg[3];
      area_a[i] = (ax2[i] - ax1[i]) * (ay2[i] - ay1[i]);
    }
    float bi[TG], bu[TG]; int bp[TG];
#pragma unroll
    for (int i = 0; i < TG; i++) { bi[i] = -1.f; bu[i] = 1.f; bp[i] = 0x7FFFFFFF; }
    int pend = (h + 1) * PHALF;
    for (int p = h * PHALF + tid; p < pend; p += 256) {
      float4 pr = reinterpret_cast<const float4*>(priors)[p];
      float px1 = pr.x - pr.z * 0.5f, py1 = pr.y - pr.w * 0.5f;
      float px2 = pr.x + pr.z * 0.5f, py2 = pr.y + pr.w * 0.5f;
      float area_b = (px2 - px1) * (py2 - py1);
#pragma unroll
      for (int i = 0; i < TG; i++) {
        float lx = fmaxf(ax1[i], px1), ly = fmaxf(ay1[i], py1);
        float rx = fminf(ax2[i], px2), ry = fminf(ay2[i], py2);
        float w = fmaxf(rx - lx, 0.f), h2 = fmaxf(ry - ly, 0.f);
        float inter = w * h2;
        float uni = area_a[i] + area_b - inter;
        if (inter * bu[i] > bi[i] * uni) { bi[i] = inter; bu[i] = uni; bp[i] = p; }
      }
    }
#pragma unroll
    for (int off = 1; off < 64; off <<= 1) {
#pragma unroll
      for (int i = 0; i < TG; i++) {
        float oi = __shfl_xor(bi[i], off), ou = __shfl_xor(bu[i], off);
        int op = __shfl_xor(bp[i], off);
        float a = oi * bu[i], c = bi[i] * ou;
        if (a > c || (a == c && op < bp[i])) { bi[i] = oi; bu[i] = ou; bp[i] = op; }
      }
    }
    __shared__ float si[TG][4], su[TG][4];
    __shared__ int spx[TG][4];
    int w = tid >> 6;
    if ((tid & 63) == 0) {
#pragma unroll
      for (int i = 0; i < TG; i++) { si[i][w] = bi[i]; su[i][w] = bu[i]; spx[i][w] = bp[i]; }
    }
    __syncthreads();
    if (tid < TG) {
      float fi = si[tid][0], fu = su[tid][0]; int fp = spx[tid][0];
      for (int ww = 1; ww < 4; ww++) {
        float a = si[tid][ww] * fu, c = fi * su[tid][ww];
        if (a > c || (a == c && spx[tid][ww] < fp)) { fi = si[tid][ww]; fu = su[tid][ww]; fp = spx[tid][ww]; }
      }
      float q = fi / fu;
      unsigned long long key = ((unsigned long long)f2key(q) << 32) | (unsigned)(~fp);
      bpp[((long)b * ON + t0 + tid) * PSPLIT + h] = key;
    }
  }
}

// ===== K2: mega-select — scatter-fix + inline encode + histogram select + final =====
__global__ void __launch_bounds__(1024) k_megasel(const float* __restrict__ priors,
                                                  const float* __restrict__ targets,
                                                  const float* __restrict__ loc_data,
                                                  const float* __restrict__ conf_data,
                                                  const float* __restrict__ landm_data,
                                                  const float* __restrict__ bto,
                                                  const int* __restrict__ bti,
                                                  const unsigned long long* __restrict__ bpp,
                                                  float* __restrict__ lossc,
                                                  unsigned char* __restrict__ posf,
                                                  GAcc* __restrict__ gacc,
                                                  float* __restrict__ out) {
  int b = blockIdx.x;
  int tid = threadIdx.x;
  int lane = tid & 63;
  int wv = tid >> 6;
  __shared__ float4 tgs4[ON * 15 / 4];     // 960 floats: targets row
  __shared__ unsigned bitmap[BMW];
  __shared__ int fixq[ON];
  __shared__ int fixinfo[ON];
  __shared__ unsigned hist[NBINS];
  __shared__ unsigned wtot[16];
  __shared__ float wsl[16], wslm[16];
  __shared__ unsigned wnp[16], wnp1[16];
  __shared__ float resv[MAXM];
  __shared__ int residx[MAXM];
  __shared__ int s_B, s_kp;
  __shared__ unsigned s_mc;
  float* tgs = (float*)tgs4;
  const float* row = &lossc[(long)b * PN];
  const unsigned char* prow = &posf[(long)b * PN];

  for (int i = tid; i < NBINS; i += 1024) hist[i] = 0;
  for (int i = tid; i < BMW; i += 1024) bitmap[i] = 0;
  if (tid < ON * 15 / 4)
    tgs4[tid] = reinterpret_cast<const float4*>(targets + (long)b * ON * 15)[tid];
  __syncthreads();

  // ---- wave 0: scatter winners (last-write-wins via dupLater shuffle) ----
  if (tid < ON) {
    int t = tid;
    unsigned long long v0 = bpp[((long)b * ON + t) * PSPLIT];
    unsigned long long v1 = bpp[((long)b * ON + t) * PSPLIT + 1];
    unsigned long long best = v0 > v1 ? v0 : v1;
    float q = key2f((unsigned)(best >> 32));
    int qp = (int)(~(unsigned)best);
    bool valid = q >= 0.2f;
    bool dupLater = false;
    for (int j = 0; j < 64; j++) {
      int ij = __shfl(qp, j);
      if (j > t && ij == qp) dupLater = true;
    }
    fixq[t] = dupLater ? -1 : qp;
    fixinfo[t] = (t << 1) | (valid ? 1 : 0);
    if (!dupLater) atomicOr(&bitmap[qp >> 5], 1u << (qp & 31));
  }
  __syncthreads();

  // ---- inline encode: thread owns priors [tid*16, tid*16+16) + tail ----
  const float4* bto4 = reinterpret_cast<const float4*>(bto + (long)b * PN);
  const int4* bti4 = reinterpret_cast<const int4*>(bti + (long)b * PN);
  const float4* cf4 = reinterpret_cast<const float4*>(conf_data + (long)b * PN * 2);
  float4* lc4 = reinterpret_cast<float4*>(lossc + (long)b * PN);
  bool hasTail = tid < TAILT;

  float vm[16], vt[4];
  unsigned pmask = 0, tmask = 0;
  float sum_l = 0.f, sum_lm = 0.f;
  unsigned cp = 0, cp1 = 0;

#pragma unroll
  for (int g4 = 0; g4 < 4; g4++) {
    float4 O = bto4[tid * 4 + g4];
    int4 T = bti4[tid * 4 + g4];
    float4 Ca = cf4[tid * 8 + 2 * g4], Cb = cf4[tid * 8 + 2 * g4 + 1];
    float ox[4] = {O.x, O.y, O.z, O.w};
    int tx[4] = {T.x, T.y, T.z, T.w};
    float xa[4] = {Ca.x, Ca.z, Cb.x, Cb.z};
    float xb[4] = {Ca.y, Ca.w, Cb.y, Cb.w};
#pragma unroll
    for (int jj = 0; jj < 4; jj++) {
      int j = g4 * 4 + jj;
      int p = tid * 16 + j;
      int t = tx[jj];
      float ov = ox[jj];
      if ((bitmap[p >> 5] >> (p & 31)) & 1u) {
        for (int s = 0; s < ON; s++)
          if (fixq[s] == p) { int inf = fixinfo[s]; t = inf >> 1; if (inf & 1) ov = 2.0f; }
      }
      const float* tg = &tgs[t * 15];
      bool pos = ov >= THRESH;
      if (pos) {
        long gp = (long)b * PN + p;
        float4 pr = reinterpret_cast<const float4*>(priors)[p];
        float rz = 1.0f / pr.z, rw = 1.0f / pr.w;
        float m0 = tg[0], m1 = tg[1], m2 = tg[2], m3 = tg[3];
        float g0 = ((m0 + m2) * 0.5f - pr.x) * rz * 10.f;
        float g1 = ((m1 + m3) * 0.5f - pr.y) * rw * 10.f;
        float g2 = __logf((m2 - m0) * rz) * 5.f;
        float g3 = __logf((m3 - m1) * rw) * 5.f;
        const float* ld = &loc_data[gp * 4];
        sum_l += sl1(ld[0] - g0) + sl1(ld[1] - g1) + sl1(ld[2] - g2) + sl1(ld[3] - g3);
        cp++;
        if (tg[14] > 0.f) {
          const float* lm = &landm_data[gp * 10];
#pragma unroll
          for (int i = 0; i < 5; i++) {
            float gx = (tg[4 + 2 * i] - pr.x) * rz * 10.f;
            float gy = (tg[5 + 2 * i] - pr.y) * rw * 10.f;
            sum_lm += sl1(lm[2 * i] - gx) + sl1(lm[2 * i + 1] - gy);
          }
          cp1++;
        }
      }
      float x0 = xa[jj], x1 = xb[jj];
      float mm = fmaxf(x0, x1);
      float lse = mm + __logf(__expf(x0 - mm) + __expf(x1 - mm));
      vm[j] = lse - (pos ? x1 : x0);
      if (pos) pmask |= 1u << j;
    }
    lc4[tid * 4 + g4] = make_float4(vm[g4 * 4], vm[g4 * 4 + 1], vm[g4 * 4 + 2], vm[g4 * 4 + 3]);
  }
  {
    unsigned pw0 = ((pmask >> 0) & 1u) | (((pmask >> 1) & 1u) << 8) | (((pmask >> 2) & 1u) << 16) | (((pmask >> 3) & 1u) << 24);
    unsigned pw1 = ((pmask >> 4) & 1u) | (((pmask >> 5) & 1u) << 8) | (((pmask >> 6) & 1u) << 16) | (((pmask >> 7) & 1u) << 24);
    unsigned pw2 = ((pmask >> 8) & 1u) | (((pmask >> 9) & 1u) << 8) | (((pmask >> 10) & 1u) << 16) | (((pmask >> 11) & 1u) << 24);
    unsigned pw3 = ((pmask >> 12) & 1u) | (((pmask >> 13) & 1u) << 8) | (((pmask >> 14) & 1u) << 16) | (((pmask >> 15) & 1u) << 24);
    reinterpret_cast<uint4*>(posf + (long)b * PN)[tid] = make_uint4(pw0, pw1, pw2, pw3);
  }
  if (hasTail) {
    float4 Ot = bto4[4096 + tid];
    int4 Tt = bti4[4096 + tid];
    float4 Ca = cf4[8192 + tid * 2], Cb = cf4[8192 + tid * 2 + 1];
    float ox[4] = {Ot.x, Ot.y, Ot.z, Ot.w};
    int tx[4] = {Tt.x, Tt.y, Tt.z, Tt.w};
    float xa[4] = {Ca.x, Ca.z, Cb.x, Cb.z};
    float xb[4] = {Ca.y, Ca.w, Cb.y, Cb.w};
#pragma unroll
    for (int jj = 0; jj < 4; jj++) {
      int p = 16384 + tid * 4 + jj;
      int t = tx[jj];
      float ov = ox[jj];
      if ((bitmap[p >> 5] >> (p & 31)) & 1u) {
        for (int s = 0; s < ON; s++)
          if (fixq[s] == p) { int inf = fixinfo[s]; t = inf >> 1; if (inf & 1) ov = 2.0f; }
      }
      const float* tg = &tgs[t * 15];
      bool pos = ov >= THRESH;
      if (pos) {
        long gp = (long)b * PN + p;
        float4 pr = reinterpret_cast<const float4*>(priors)[p];
        float rz = 1.0f / pr.z, rw = 1.0f / pr.w;
        float m0 = tg[0], m1 = tg[1], m2 = tg[2], m3 = tg[3];
        float g0 = ((m0 + m2) * 0.5f - pr.x) * rz * 10.f;
        float g1 = ((m1 + m3) * 0.5f - pr.y) * rw * 10.f;
        float g2 = __logf((m2 - m0) * rz) * 5.f;
        float g3 = __logf((m3 - m1) * rw) * 5.f;
        const float* ld = &loc_data[gp * 4];
        sum_l += sl1(ld[0] - g0) + sl1(ld[1] - g1) + sl1(ld[2] - g2) + sl1(ld[3] - g3);
        cp++;
        if (tg[14] > 0.f) {
          const float* lm = &landm_data[gp * 10];
#pragma unroll
          for (int i = 0; i < 5; i++) {
            float gx = (tg[4 + 2 * i] - pr.x) * rz * 10.f;
            float gy = (tg[5 + 2 * i] - pr.y) * rw * 10.f;
            sum_lm += sl1(lm[2 * i] - gx) + sl1(lm[2 * i + 1] - gy);
          }
          cp1++;
        }
      }
      float x0 = xa[jj], x1 = xb[jj];
      float mm = fmaxf(x0, x1);
      float lse = mm + __logf(__expf(x0 - mm) + __expf(x1 - mm));
      vt[jj] = lse - (pos ? x1 : x0);
      if (pos) tmask |= 1u << jj;
    }
    lc4[4096 + tid] = make_float4(vt[0], vt[1], vt[2], vt[3]);
    unsigned tw = ((tmask >> 0) & 1u) | (((tmask >> 1) & 1u) << 8) | (((tmask >> 2) & 1u) << 16) | (((tmask >> 3) & 1u) << 24);
    reinterpret_cast<unsigned*>(posf + (long)b * PN)[4096 + tid] = tw;
  } else {
    vt[0] = vt[1] = vt[2] = vt[3] = -1.f;
  }

  // ---- block-reduce np/sl/slm/np1 (np needed before k) ----
  {
    float rsl = sum_l, rslm = sum_lm;
    unsigned rnp = cp, rnp1 = cp1;
#pragma unroll
    for (int o = 32; o; o >>= 1) {
      rsl += __shfl_down(rsl, o);
      rslm += __shfl_down(rslm, o);
      rnp += (unsigned)__shfl_down((int)rnp, o);
      rnp1 += (unsigned)__shfl_down((int)rnp1, o);
    }
    if (lane == 0) { wsl[wv] = rsl; wslm[wv] = rslm; wnp[wv] = rnp; wnp1[wv] = rnp1; }
  }
  __syncthreads();
  unsigned npTot = 0;
  for (int i = 0; i < 16; i++) npTot += wnp[i];
  int np = (int)npTot;
  int k = NEGPOS * np;
  if (k > PN - 1) k = PN - 1;
  bool haveNeg = (k > 0);

  // ---- quantize ----
  int bm[16], bt4[4];
#pragma unroll
  for (int j = 0; j < 16; j++) {
    int q = (int)(vm[j] * 256.0f);
    bm[j] = q < 0 ? 0 : (q > NBINS - 1 ? NBINS - 1 : q);
  }
#pragma unroll
  for (int j = 0; j < 4; j++) {
    int q = (int)(vt[j] * 256.0f);
    bt4[j] = q < 0 ? 0 : (q > NBINS - 1 ? NBINS - 1 : q);
  }

  int B = NBINS, kp = 0, m = 0;
  bool allB = false, fallback = false;
  if (haveNeg) {
#pragma unroll
    for (int j = 0; j < 16; j++) atomicAdd(&hist[bm[j]], 1u);
    if (hasTail) {
#pragma unroll
      for (int j = 0; j < 4; j++) atomicAdd(&hist[bt4[j]], 1u);
    }
    __syncthreads();
    int t4 = tid * 4;
    unsigned h0 = hist[t4], h1 = hist[t4 + 1], h2 = hist[t4 + 2], h3 = hist[t4 + 3];
    unsigned th = h0 + h1 + h2 + h3;
    unsigned v = th;
#pragma unroll
    for (int off = 1; off < 64; off <<= 1) {
      unsigned tv = (unsigned)__shfl_down((int)v, off);
      if (lane + off < 64) v += tv;
    }
    if (lane == 0) wtot[wv] = v;
    __syncthreads();
    unsigned add = 0;
    for (int w2 = wv + 1; w2 < 16; w2++) add += wtot[w2];
    unsigned S_t = v + add;
    unsigned S_next = S_t - th;
    if (S_t >= (unsigned)k && S_next < (unsigned)k) {
      unsigned run = S_next; int Bl; unsigned kpl;
      if (run + h3 >= (unsigned)k) { Bl = t4 + 3; kpl = k - run; }
      else { run += h3;
        if (run + h2 >= (unsigned)k) { Bl = t4 + 2; kpl = k - run; }
        else { run += h2;
          if (run + h1 >= (unsigned)k) { Bl = t4 + 1; kpl = k - run; }
          else { run += h1; Bl = t4; kpl = k - run; } } }
      s_B = Bl; s_kp = (int)kpl;
    }
    __syncthreads();
    B = s_B; kp = s_kp; m = (int)hist[B];
    allB = (kp == m);
    fallback = (!allB && m > MAXM);
  }

  float acc = 0.f;
  if (haveNeg && !allB && !fallback) {
    if (tid == 0) s_mc = 0;
    __syncthreads();
#pragma unroll
    for (int j = 0; j < 16; j++) {
      if (bm[j] == B) {
        unsigned slot = atomicAdd(&s_mc, 1u);
        resv[slot] = vm[j];
        residx[slot] = (tid * 16 + j) | (((pmask >> j) & 1u) ? 0x40000000 : 0);
      }
    }
    if (hasTail) {
#pragma unroll
      for (int j = 0; j < 4; j++) {
        if (bt4[j] == B) {
          unsigned slot = atomicAdd(&s_mc, 1u);
          resv[slot] = vt[j];
          residx[slot] = (16384 + tid * 4 + j) | (((tmask >> j) & 1u) ? 0x40000000 : 0);
        }
      }
    }
    __syncthreads();
    for (int i = tid; i < m; i += 1024) {
      float vi = resv[i];
      int pk = residx[i];
      int ii = pk & 0x3FFFFFFF;
      bool posi = (pk & 0x40000000) != 0;
      int rank = 0;
      for (int j = 0; j < m; j++) {
        float vj = resv[j];
        int ij = residx[j] & 0x3FFFFFFF;
        rank += (vj > vi || (vj == vi && ij < ii)) ? 1 : 0;
      }
      if (rank < kp && !posi) acc += vi;
    }
  }

  unsigned T = 0, R = 0, C = 0;
  if (fallback) {
    // rare: exact 32-bit bisection; tie path reads global lossc/posf (written above)
    __shared__ unsigned s_lo, s_hi, fcnt[16];
    if (tid == 0) { s_lo = 0u; s_hi = 0xFFFFFFFFu; }
    __syncthreads();
    for (int it = 0; it < 32; it++) {
      unsigned lo = s_lo, hi = s_hi;
      unsigned mid = lo + ((hi - lo) >> 1) + ((hi - lo) & 1u);
      unsigned c = 0;
#pragma unroll
      for (int j = 0; j < 16; j++) c += (f2key(vm[j]) >= mid) ? 1u : 0u;
      if (hasTail) {
#pragma unroll
        for (int j = 0; j < 4; j++) c += (f2key(vt[j]) >= mid) ? 1u : 0u;
      }
#pragma unroll
      for (int o = 32; o; o >>= 1) c += (unsigned)__shfl_down((int)c, o);
      if (lane == 0) fcnt[wv] = c;
      __syncthreads();
      if (tid == 0) {
        unsigned tot = 0;
        for (int i = 0; i < 16; i++) tot += fcnt[i];
        if (tot >= (unsigned)k) s_lo = mid; else s_hi = mid - 1;
      }
      __syncthreads();
      if (s_lo >= s_hi) break;
    }
    T = s_lo;
    unsigned cg = 0, ce = 0;
#pragma unroll
    for (int j = 0; j < 16; j++) {
      unsigned key = f2key(vm[j]);
      cg += (key > T) ? 1u : 0u;
      ce += (key == T) ? 1u : 0u;
    }
    if (hasTail) {
#pragma unroll
      for (int j = 0; j < 4; j++) {
        unsigned key = f2key(vt[j]);
        cg += (key > T) ? 1u : 0u;
        ce += (key == T) ? 1u : 0u;
      }
    }
#pragma unroll
    for (int o = 32; o; o >>= 1) {
      cg += (unsigned)__shfl_down((int)cg, o);
      ce += (unsigned)__shfl_down((int)ce, o);
    }
    if (lane == 0) { fcnt[wv] = cg; wtot[wv] = ce; }
    __syncthreads();
    if (tid == 0) {
      unsigned tg2 = 0, te = 0;
      for (int i = 0; i < 16; i++) { tg2 += fcnt[i]; te += wtot[i]; }
      fcnt[0] = tg2; wtot[0] = te;
    }
    __syncthreads();
    C = wtot[0];
    R = (unsigned)k - fcnt[0];
    if (C != R && tid < 64) {
      unsigned running = 0;
      for (int base2 = 0; base2 < PN; base2 += 64) {
        int p = base2 + tid;
        bool tie = false, pos = false;
        float v2 = 0.f;
        if (p < PN) { v2 = row[p]; tie = (f2key(v2) == T); pos = prow[p] != 0; }
        unsigned long long mm = __ballot(tie);
        if (tie) {
          unsigned rank = running + (unsigned)__popcll(mm & ((1ull << tid) - 1));
          if (rank < R && !pos) acc += v2;
        }
        running += (unsigned)__popcll(mm);
      }
    }
  }

  unsigned ptc = 0;
#pragma unroll
  for (int j = 0; j < 16; j++) {
    float v2 = vm[j];
    bool pos = (pmask >> j) & 1u;
    if (pos) acc += v2;
    else if (haveNeg) {
      if (!fallback) {
        if (bm[j] > B || (bm[j] == B && allB)) acc += v2;
      } else {
        if (f2key(v2) > T) acc += v2;
      }
    }
    if (fallback && pos && f2key(v2) == T) ptc++;
  }
  if (hasTail) {
#pragma unroll
    for (int j = 0; j < 4; j++) {
      float v2 = vt[j];
      bool pos = (tmask >> j) & 1u;
      if (pos) acc += v2;
      else if (haveNeg) {
        if (!fallback) {
          if (bt4[j] > B || (bt4[j] == B && allB)) acc += v2;
        } else {
          if (f2key(v2) > T) acc += v2;
        }
      }
      if (fallback && pos && f2key(v2) == T) ptc++;
    }
  }
  {
#pragma unroll
    for (int o = 32; o; o >>= 1) {
      acc += __shfl_down(acc, o);
      ptc += (unsigned)__shfl_down((int)ptc, o);
    }
  }
  __shared__ float wsum[16];
  __shared__ unsigned wpt[16];
  if (lane == 0) { wsum[wv] = acc; wpt[wv] = ptc; }
  __syncthreads();

  if (tid == 0) {
    float tot = 0.f; unsigned pt = 0;
    float tsl = 0.f, tslm = 0.f; unsigned tnp1 = 0;
    for (int i = 0; i < 16; i++) {
      tot += wsum[i]; pt += wpt[i];
      tsl += wsl[i]; tslm += wslm[i]; tnp1 += wnp1[i];
    }
    if (fallback && C == R) tot += (float)(C - pt) * key2f(T);
    atomicAdd(&gacc->sc, tot);
    atomicAdd(&gacc->sl, tsl);
    atomicAdd(&gacc->slm, tslm);
    atomicAdd(&gacc->np, np);
    atomicAdd(&gacc->np1, (int)tnp1);
  }
  __threadfence();
  __shared__ int lastF;
  if (tid == 0) lastF = (atomicAdd(&gacc->ticket, 1u) == (unsigned)(BN - 1)) ? 1 : 0;
  __syncthreads();
  if (lastF && tid == 0) {
    __threadfence();
    float sl = atomicAdd(&gacc->sl, 0.f);
    float slm = atomicAdd(&gacc->slm, 0.f);
    float sc = atomicAdd(&gacc->sc, 0.f);
    int tnp = atomicAdd(&gacc->np, 0);
    int tnp1 = atomicAdd(&gacc->np1, 0);
    float N = fmaxf((float)tnp, 1.f);
    float N1 = fmaxf((float)tnp1, 1.f);
    out[0] = sl / N;
    out[1] = sc / N;
    out[2] = slm / N1;
  }
}

extern "C" void kernel_launch(void* const* d_in, const int* in_sizes, int n_in,
                              void* d_out, int out_size, void* d_ws, size_t ws_size,
                              hipStream_t stream) {
  const float* loc_data = (const float*)d_in[0];
  const float* conf_data = (const float*)d_in[1];
  const float* landm_data = (const float*)d_in[2];
  const float* priors = (const float*)d_in[3];
  const float* targets = (const float*)d_in[4];
  float* out = (float*)d_out;

  char* ws = (char*)d_ws;
  const size_t SZ = (size_t)BN * PN * 4;
  size_t off = 0;
  float* lossc = (float*)(ws + off); off += SZ;
  float* bto = (float*)(ws + off); off += SZ;
  int* bti = (int*)(ws + off); off += SZ;
  unsigned char* posf = (unsigned char*)(ws + off); off += (size_t)BN * PN;
  off = (off + 15) & ~(size_t)15;
  unsigned long long* bpp = (unsigned long long*)(ws + off);
  off += (size_t)BN * ON * PSPLIT * 8;
  GAcc* gacc = (GAcc*)(ws + off); off += sizeof(GAcc);

  k_match2<<<NBT + NBP2, 256, 0, stream>>>(priors, targets, bto, bti, bpp, gacc);
  k_megasel<<<BN, 1024, 0, stream>>>(priors, targets, loc_data, conf_data, landm_data,
                                     bto, bti, bpp, lossc, posf, gacc, out);
}

// Round 17
// 207.910 us; speedup vs baseline: 1.1646x; 1.1646x over previous
//
#include <hip/hip_runtime.h>
#include <math.h>

#define BN 64
#define PN 16800
#define ON 64
#define THRESH 0.35f
#define NEGPOS 7
#define GX 66                  // encode blocks per row (66*256 >= 16800)
#define NBLK (BN * GX)         // 4224 partial slots
#define GXB 17                 // best_truth blocks per row (1024 priors/block, 4/thread)
#define NBT (BN * GXB)         // 1088 bt blocks
#define PT 4                   // priors per thread in best_truth
#define TG 4                   // truths per block in best_prior
#define PSPLIT 2               // bp priors split
#define PHALF 8400
#define NBP2 (BN * 16 * PSPLIT) // 2048 bp blocks
#define NBINS 4096
#define MAXM 4096
#define TAILT 104              // threads with tail work in select (416/4)

struct GAcc {
  unsigned ticket;
  float sl, slm, sc;
  int np, np1;
  unsigned pad0, pad1;
};

__device__ __forceinline__ unsigned f2key(float f) {
  unsigned u = __float_as_uint(f);
  return (u & 0x80000000u) ? ~u : (u | 0x80000000u);
}
__device__ __forceinline__ float key2f(unsigned k) {
  unsigned u = (k & 0x80000000u) ? (k & 0x7FFFFFFFu) : ~k;
  return __uint_as_float(u);
}
__device__ __forceinline__ float sl1(float d) {
  float a = fabsf(d);
  return (a < 1.f) ? 0.5f * a * a : a - 0.5f;
}

// ====== K1: combined grid — best_truth blocks + split best_prior blocks ======
__global__ void k_match2(const float* __restrict__ priors,
                         const float* __restrict__ targets,
                         float* __restrict__ bto, int* __restrict__ bti,
                         unsigned long long* __restrict__ bpp,
                         GAcc* __restrict__ gacc) {
  int bid = blockIdx.x;
  int tid = threadIdx.x;

  if (bid < NBT) {
    int b = bid / GXB;
    int slab = bid - b * GXB;
    int base = slab * 1024 + tid;
    if (bid == 0 && tid < 8) ((unsigned*)gacc)[tid] = 0;

    __shared__ float4 tbox[ON];
    __shared__ float tarea[ON];
    if (tid < ON) {
      const float* tg = &targets[((long)b * ON + tid) * 15];
      float4 bx = make_float4(tg[0], tg[1], tg[2], tg[3]);
      tbox[tid] = bx;
      tarea[tid] = (bx.z - bx.x) * (bx.w - bx.y);
    }
    __syncthreads();

    float px1[PT], py1[PT], px2[PT], py2[PT], ab[PT];
    bool val[PT];
#pragma unroll
    for (int i = 0; i < PT; i++) {
      int p = base + 256 * i;
      val[i] = p < PN;
      float4 pr = reinterpret_cast<const float4*>(priors)[val[i] ? p : base];
      px1[i] = pr.x - pr.z * 0.5f; py1[i] = pr.y - pr.w * 0.5f;
      px2[i] = pr.x + pr.z * 0.5f; py2[i] = pr.y + pr.w * 0.5f;
      ab[i] = (px2[i] - px1[i]) * (py2[i] - py1[i]);
    }
    float bi[PT], bu[PT]; int id[PT];
#pragma unroll
    for (int i = 0; i < PT; i++) { bi[i] = -1.f; bu[i] = 1.f; id[i] = 0; }

#pragma unroll 4
    for (int t = 0; t < ON; t++) {
      float4 a = tbox[t];
      float aa = tarea[t];
#pragma unroll
      for (int i = 0; i < PT; i++) {
        float lx = fmaxf(a.x, px1[i]), ly = fmaxf(a.y, py1[i]);
        float rx = fminf(a.z, px2[i]), ry = fminf(a.w, py2[i]);
        float w = fmaxf(rx - lx, 0.f), h = fmaxf(ry - ly, 0.f);
        float inter = w * h;
        float uni = aa + ab[i] - inter;
        if (inter * bu[i] > bi[i] * uni) { bi[i] = inter; bu[i] = uni; id[i] = t; }
      }
    }
#pragma unroll
    for (int i = 0; i < PT; i++) {
      if (val[i]) {
        int p = base + 256 * i;
        bto[(long)b * PN + p] = bi[i] / bu[i];
        bti[(long)b * PN + p] = id[i];
      }
    }
  } else {
    int id2 = bid - NBT;
    int b = id2 >> 5;
    int rest = id2 & 31;
    int g = rest >> 1;
    int h = rest & 1;
    int t0 = g * TG;
    float ax1[TG], ay1[TG], ax2[TG], ay2[TG], area_a[TG];
#pragma unroll
    for (int i = 0; i < TG; i++) {
      const float* tg = &targets[((long)b * ON + t0 + i) * 15];
      ax1[i] = tg[0]; ay1[i] = tg[1]; ax2[i] = tg[2]; ay2[i] = tg[3];
      area_a[i] = (ax2[i] - ax1[i]) * (ay2[i] - ay1[i]);
    }
    float bi[TG], bu[TG]; int bp[TG];
#pragma unroll
    for (int i = 0; i < TG; i++) { bi[i] = -1.f; bu[i] = 1.f; bp[i] = 0x7FFFFFFF; }
    int pend = (h + 1) * PHALF;
    for (int p = h * PHALF + tid; p < pend; p += 256) {
      float4 pr = reinterpret_cast<const float4*>(priors)[p];
      float px1 = pr.x - pr.z * 0.5f, py1 = pr.y - pr.w * 0.5f;
      float px2 = pr.x + pr.z * 0.5f, py2 = pr.y + pr.w * 0.5f;
      float area_b = (px2 - px1) * (py2 - py1);
#pragma unroll
      for (int i = 0; i < TG; i++) {
        float lx = fmaxf(ax1[i], px1), ly = fmaxf(ay1[i], py1);
        float rx = fminf(ax2[i], px2), ry = fminf(ay2[i], py2);
        float w = fmaxf(rx - lx, 0.f), h2 = fmaxf(ry - ly, 0.f);
        float inter = w * h2;
        float uni = area_a[i] + area_b - inter;
        if (inter * bu[i] > bi[i] * uni) { bi[i] = inter; bu[i] = uni; bp[i] = p; }
      }
    }
#pragma unroll
    for (int off = 1; off < 64; off <<= 1) {
#pragma unroll
      for (int i = 0; i < TG; i++) {
        float oi = __shfl_xor(bi[i], off), ou = __shfl_xor(bu[i], off);
        int op = __shfl_xor(bp[i], off);
        float a = oi * bu[i], c = bi[i] * ou;
        if (a > c || (a == c && op < bp[i])) { bi[i] = oi; bu[i] = ou; bp[i] = op; }
      }
    }
    __shared__ float si[TG][4], su[TG][4];
    __shared__ int spx[TG][4];
    int w = tid >> 6;
    if ((tid & 63) == 0) {
#pragma unroll
      for (int i = 0; i < TG; i++) { si[i][w] = bi[i]; su[i][w] = bu[i]; spx[i][w] = bp[i]; }
    }
    __syncthreads();
    if (tid < TG) {
      float fi = si[tid][0], fu = su[tid][0]; int fp = spx[tid][0];
      for (int ww = 1; ww < 4; ww++) {
        float a = si[tid][ww] * fu, c = fi * su[tid][ww];
        if (a > c || (a == c && spx[tid][ww] < fp)) { fi = si[tid][ww]; fu = su[tid][ww]; fp = spx[tid][ww]; }
      }
      float q = fi / fu;
      unsigned long long key = ((unsigned long long)f2key(q) << 32) | (unsigned)(~fp);
      bpp[((long)b * ON + t0 + tid) * PSPLIT + h] = key;
    }
  }
}

// ================= K2: encode + half-combine scatter + partials =================
__global__ void k_encode(const float* __restrict__ loc_data,
                         const float* __restrict__ conf_data,
                         const float* __restrict__ landm_data,
                         const float* __restrict__ priors,
                         const float* __restrict__ targets,
                         const float* __restrict__ bto, const int* __restrict__ bti,
                         const unsigned long long* __restrict__ bpp,
                         float* __restrict__ lossc, unsigned char* __restrict__ posf,
                         float* __restrict__ part_l, float* __restrict__ part_lm,
                         int* __restrict__ np_part, int* __restrict__ np1_part) {
  int b = blockIdx.y;
  int p = blockIdx.x * 256 + threadIdx.x;
  int bid = b * GX + blockIdx.x;
  __shared__ float4 tgs4[ON * 15 / 4];
  __shared__ int ovr[256];
  float* tgs = (float*)tgs4;
  if (threadIdx.x < ON * 15 / 4)
    tgs4[threadIdx.x] = reinterpret_cast<const float4*>(targets + (long)b * ON * 15)[threadIdx.x];
  ovr[threadIdx.x] = -1;
  __syncthreads();
  if (threadIdx.x < ON) {
    int t = threadIdx.x;
    unsigned long long v0 = bpp[((long)b * ON + t) * PSPLIT];
    unsigned long long v1 = bpp[((long)b * ON + t) * PSPLIT + 1];
    unsigned long long best = v0 > v1 ? v0 : v1;
    float q = key2f((unsigned)(best >> 32));
    int qp = (int)(~(unsigned)best);
    int s0 = blockIdx.x * 256;
    if (qp >= s0 && qp < s0 + 256) {
      int valid = (q >= 0.2f) ? 1 : 0;
      atomicMax(&ovr[qp - s0], (t << 1) | valid);
    }
  }
  __syncthreads();

  float sum_l = 0.f, sum_lm = 0.f;
  int cp = 0, cp1 = 0;
  if (p < PN) {
    int t = bti[b * PN + p];
    float ov = bto[b * PN + p];
    int o = ovr[threadIdx.x];
    if (o >= 0) { t = o >> 1; if (o & 1) ov = 2.0f; }
    const float* tg = &tgs[t * 15];
    float label = tg[14];
    bool pos = ov >= THRESH;
    bool pos1 = pos && (label > 0.f);
    float4 pr = reinterpret_cast<const float4*>(priors)[p];
    if (pos) {
      float rz = 1.0f / pr.z, rw = 1.0f / pr.w;
      float m0 = tg[0], m1 = tg[1], m2 = tg[2], m3 = tg[3];
      float g0 = ((m0 + m2) * 0.5f - pr.x) * rz * 10.f;
      float g1 = ((m1 + m3) * 0.5f - pr.y) * rw * 10.f;
      float g2 = __logf((m2 - m0) * rz) * 5.f;
      float g3 = __logf((m3 - m1) * rw) * 5.f;
      const float* ld = &loc_data[((long)b * PN + p) * 4];
      sum_l = sl1(ld[0] - g0) + sl1(ld[1] - g1) + sl1(ld[2] - g2) + sl1(ld[3] - g3);
      cp = 1;
      if (pos1) {
        const float* lm = &landm_data[((long)b * PN + p) * 10];
#pragma unroll
        for (int i = 0; i < 5; i++) {
          float gx = (tg[4 + 2 * i] - pr.x) * rz * 10.f;
          float gy = (tg[5 + 2 * i] - pr.y) * rw * 10.f;
          sum_lm += sl1(lm[2 * i] - gx) + sl1(lm[2 * i + 1] - gy);
        }
        cp1 = 1;
      }
    }
    float2 c2 = reinterpret_cast<const float2*>(conf_data)[(long)b * PN + p];
    float m = fmaxf(c2.x, c2.y);
    float lse = m + __logf(__expf(c2.x - m) + __expf(c2.y - m));
    lossc[b * PN + p] = lse - (pos ? c2.y : c2.x);
    posf[b * PN + p] = pos ? 1 : 0;
  }
  for (int off = 32; off; off >>= 1) {
    sum_l += __shfl_down(sum_l, off);
    sum_lm += __shfl_down(sum_lm, off);
    cp += __shfl_down(cp, off);
    cp1 += __shfl_down(cp1, off);
  }
  __shared__ float sl4[4], slm4[4];
  __shared__ int sp4[4], sp14[4];
  int w = threadIdx.x >> 6;
  if ((threadIdx.x & 63) == 0) { sl4[w] = sum_l; slm4[w] = sum_lm; sp4[w] = cp; sp14[w] = cp1; }
  __syncthreads();
  if (threadIdx.x == 0) {
    part_l[bid] = sl4[0] + sl4[1] + sl4[2] + sl4[3];
    part_lm[bid] = slm4[0] + slm4[1] + slm4[2] + slm4[3];
    np_part[bid] = sp4[0] + sp4[1] + sp4[2] + sp4[3];
    np1_part[bid] = sp14[0] + sp14[1] + sp14[2] + sp14[3];
  }
}

// ===== K3: histogram select, vectorized float4/uint4 sweep =====
__global__ void __launch_bounds__(1024) k_select(const float* __restrict__ lossc,
                                                 const unsigned char* __restrict__ posf,
                                                 const int* __restrict__ np_part,
                                                 const int* __restrict__ np1_part,
                                                 const float* __restrict__ part_l,
                                                 const float* __restrict__ part_lm,
                                                 GAcc* __restrict__ gacc,
                                                 float* __restrict__ out) {
  int b = blockIdx.x;
  int tid = threadIdx.x;
  int lane = tid & 63;
  int wv = tid >> 6;
  __shared__ unsigned hist[NBINS];
  __shared__ unsigned wtot[16];
  __shared__ float resv[MAXM];
  __shared__ int residx[MAXM];
  __shared__ int s_np, s_B, s_kp;
  __shared__ unsigned s_mc;
  const float* row = &lossc[(long)b * PN];
  const unsigned char* prow = &posf[(long)b * PN];

  if (tid == 0) s_np = 0;
  for (int i = tid; i < NBINS; i += 1024) hist[i] = 0;
  __syncthreads();
  if (tid < GX) atomicAdd(&s_np, np_part[b * GX + tid]);

  const float4* rf4 = reinterpret_cast<const float4*>(row);
  const uint4* pw4 = reinterpret_cast<const uint4*>(prow);
  bool hasTail = tid < TAILT;
  float vm[16];
  float vt[4];
  {
    float4 L0 = rf4[tid * 4], L1 = rf4[tid * 4 + 1], L2 = rf4[tid * 4 + 2], L3 = rf4[tid * 4 + 3];
    vm[0] = L0.x; vm[1] = L0.y; vm[2] = L0.z; vm[3] = L0.w;
    vm[4] = L1.x; vm[5] = L1.y; vm[6] = L1.z; vm[7] = L1.w;
    vm[8] = L2.x; vm[9] = L2.y; vm[10] = L2.z; vm[11] = L2.w;
    vm[12] = L3.x; vm[13] = L3.y; vm[14] = L3.z; vm[15] = L3.w;
  }
  unsigned pmask = 0;
  {
    uint4 W = pw4[tid];
    unsigned w0 = W.x, w1 = W.y, w2 = W.z, w3 = W.w;
#pragma unroll
    for (int j = 0; j < 4; j++) {
      pmask |= ((w0 >> (8 * j)) & 1u) << j;
      pmask |= ((w1 >> (8 * j)) & 1u) << (4 + j);
      pmask |= ((w2 >> (8 * j)) & 1u) << (8 + j);
      pmask |= ((w3 >> (8 * j)) & 1u) << (12 + j);
    }
  }
  unsigned tmask = 0;
  if (hasTail) {
    float4 Lt = rf4[4096 + tid];
    vt[0] = Lt.x; vt[1] = Lt.y; vt[2] = Lt.z; vt[3] = Lt.w;
    unsigned Wt = reinterpret_cast<const unsigned*>(prow)[4096 + tid];
#pragma unroll
    for (int j = 0; j < 4; j++) tmask |= ((Wt >> (8 * j)) & 1u) << j;
  } else {
    vt[0] = vt[1] = vt[2] = vt[3] = -1.f;
  }
  int bm[16], bt4[4];
#pragma unroll
  for (int j = 0; j < 16; j++) {
    int q = (int)(vm[j] * 256.0f);
    bm[j] = q < 0 ? 0 : (q > NBINS - 1 ? NBINS - 1 : q);
  }
#pragma unroll
  for (int j = 0; j < 4; j++) {
    int q = (int)(vt[j] * 256.0f);
    bt4[j] = q < 0 ? 0 : (q > NBINS - 1 ? NBINS - 1 : q);
  }
  __syncthreads();
  int np = s_np;
  int k = NEGPOS * np;
  if (k > PN - 1) k = PN - 1;
  bool haveNeg = (k > 0);

  int B = NBINS, kp = 0, m = 0;
  bool allB = false, fallback = false;
  if (haveNeg) {
#pragma unroll
    for (int j = 0; j < 16; j++) atomicAdd(&hist[bm[j]], 1u);
    if (hasTail) {
#pragma unroll
      for (int j = 0; j < 4; j++) atomicAdd(&hist[bt4[j]], 1u);
    }
    __syncthreads();
    int t4 = tid * 4;
    unsigned h0 = hist[t4], h1 = hist[t4 + 1], h2 = hist[t4 + 2], h3 = hist[t4 + 3];
    unsigned th = h0 + h1 + h2 + h3;
    unsigned v = th;
#pragma unroll
    for (int off = 1; off < 64; off <<= 1) {
      unsigned tv = (unsigned)__shfl_down((int)v, off);
      if (lane + off < 64) v += tv;
    }
    if (lane == 0) wtot[wv] = v;
    __syncthreads();
    unsigned add = 0;
    for (int w2 = wv + 1; w2 < 16; w2++) add += wtot[w2];
    unsigned S_t = v + add;
    unsigned S_next = S_t - th;
    if (S_t >= (unsigned)k && S_next < (unsigned)k) {
      unsigned run = S_next; int Bl; unsigned kpl;
      if (run + h3 >= (unsigned)k) { Bl = t4 + 3; kpl = k - run; }
      else { run += h3;
        if (run + h2 >= (unsigned)k) { Bl = t4 + 2; kpl = k - run; }
        else { run += h2;
          if (run + h1 >= (unsigned)k) { Bl = t4 + 1; kpl = k - run; }
          else { run += h1; Bl = t4; kpl = k - run; } } }
      s_B = Bl; s_kp = (int)kpl;
    }
    __syncthreads();
    B = s_B; kp = s_kp; m = (int)hist[B];
    allB = (kp == m);
    fallback = (!allB && m > MAXM);
  }

  float acc = 0.f;
  if (haveNeg && !allB && !fallback) {
    if (tid == 0) s_mc = 0;
    __syncthreads();
#pragma unroll
    for (int j = 0; j < 16; j++) {
      if (bm[j] == B) {
        unsigned slot = atomicAdd(&s_mc, 1u);
        resv[slot] = vm[j];
        residx[slot] = (tid * 16 + j) | (((pmask >> j) & 1u) ? 0x40000000 : 0);
      }
    }
    if (hasTail) {
#pragma unroll
      for (int j = 0; j < 4; j++) {
        if (bt4[j] == B) {
          unsigned slot = atomicAdd(&s_mc, 1u);
          resv[slot] = vt[j];
          residx[slot] = (16384 + tid * 4 + j) | (((tmask >> j) & 1u) ? 0x40000000 : 0);
        }
      }
    }
    __syncthreads();
    for (int i = tid; i < m; i += 1024) {
      float vi = resv[i];
      int pk = residx[i];
      int ii = pk & 0x3FFFFFFF;
      bool posi = (pk & 0x40000000) != 0;
      int rank = 0;
      for (int j = 0; j < m; j++) {
        float vj = resv[j];
        int ij = residx[j] & 0x3FFFFFFF;
        rank += (vj > vi || (vj == vi && ij < ii)) ? 1 : 0;
      }
      if (rank < kp && !posi) acc += vi;
    }
  }

  unsigned T = 0, R = 0, C = 0;
  if (fallback) {
    __shared__ unsigned s_lo, s_hi, fcnt[16];
    if (tid == 0) { s_lo = 0u; s_hi = 0xFFFFFFFFu; }
    __syncthreads();
    for (int it = 0; it < 32; it++) {
      unsigned lo = s_lo, hi = s_hi;
      unsigned mid = lo + ((hi - lo) >> 1) + ((hi - lo) & 1u);
      unsigned c = 0;
#pragma unroll
      for (int j = 0; j < 16; j++) c += (f2key(vm[j]) >= mid) ? 1u : 0u;
      if (hasTail) {
#pragma unroll
        for (int j = 0; j < 4; j++) c += (f2key(vt[j]) >= mid) ? 1u : 0u;
      }
#pragma unroll
      for (int o = 32; o; o >>= 1) c += (unsigned)__shfl_down((int)c, o);
      if (lane == 0) fcnt[wv] = c;
      __syncthreads();
      if (tid == 0) {
        unsigned tot = 0;
        for (int i = 0; i < 16; i++) tot += fcnt[i];
        if (tot >= (unsigned)k) s_lo = mid; else s_hi = mid - 1;
      }
      __syncthreads();
      if (s_lo >= s_hi) break;
    }
    T = s_lo;
    unsigned cg = 0, ce = 0;
#pragma unroll
    for (int j = 0; j < 16; j++) {
      unsigned key = f2key(vm[j]);
      cg += (key > T) ? 1u : 0u;
      ce += (key == T) ? 1u : 0u;
    }
    if (hasTail) {
#pragma unroll
      for (int j = 0; j < 4; j++) {
        unsigned key = f2key(vt[j]);
        cg += (key > T) ? 1u : 0u;
        ce += (key == T) ? 1u : 0u;
      }
    }
#pragma unroll
    for (int o = 32; o; o >>= 1) {
      cg += (unsigned)__shfl_down((int)cg, o);
      ce += (unsigned)__shfl_down((int)ce, o);
    }
    if (lane == 0) { fcnt[wv] = cg; wtot[wv] = ce; }
    __syncthreads();
    if (tid == 0) {
      unsigned tg2 = 0, te = 0;
      for (int i = 0; i < 16; i++) { tg2 += fcnt[i]; te += wtot[i]; }
      fcnt[0] = tg2; wtot[0] = te;
    }
    __syncthreads();
    C = wtot[0];
    R = (unsigned)k - fcnt[0];
    if (C != R && tid < 64) {
      unsigned running = 0;
      for (int base2 = 0; base2 < PN; base2 += 64) {
        int p = base2 + tid;
        bool tie = false, pos = false;
        float v2 = 0.f;
        if (p < PN) { v2 = row[p]; tie = (f2key(v2) == T); pos = prow[p] != 0; }
        unsigned long long mm = __ballot(tie);
        if (tie) {
          unsigned rank = running + (unsigned)__popcll(mm & ((1ull << tid) - 1));
          if (rank < R && !pos) acc += v2;
        }
        running += (unsigned)__popcll(mm);
      }
    }
  }

  unsigned ptc = 0;
#pragma unroll
  for (int j = 0; j < 16; j++) {
    float v2 = vm[j];
    bool pos = (pmask >> j) & 1u;
    if (pos) acc += v2;
    else if (haveNeg) {
      if (!fallback) {
        if (bm[j] > B || (bm[j] == B && allB)) acc += v2;
      } else {
        if (f2key(v2) > T) acc += v2;
      }
    }
    if (fallback && pos && f2key(v2) == T) ptc++;
  }
  if (hasTail) {
#pragma unroll
    for (int j = 0; j < 4; j++) {
      float v2 = vt[j];
      bool pos = (tmask >> j) & 1u;
      if (pos) acc += v2;
      else if (haveNeg) {
        if (!fallback) {
          if (bt4[j] > B || (bt4[j] == B && allB)) acc += v2;
        } else {
          if (f2key(v2) > T) acc += v2;
        }
      }
      if (fallback && pos && f2key(v2) == T) ptc++;
    }
  }
  for (int o = 32; o; o >>= 1) {
    acc += __shfl_down(acc, o);
    ptc += __shfl_down(ptc, o);
  }
  __shared__ float wsum[16];
  __shared__ unsigned wpt[16];
  if (lane == 0) { wsum[wv] = acc; wpt[wv] = ptc; }
  __syncthreads();

  __shared__ float s_rsl, s_rslm;
  __shared__ int s_rnp1;
  if (tid == 0) { s_rsl = 0.f; s_rslm = 0.f; s_rnp1 = 0; }
  __syncthreads();
  if (tid < GX) {
    atomicAdd(&s_rsl, part_l[b * GX + tid]);
    atomicAdd(&s_rslm, part_lm[b * GX + tid]);
    atomicAdd(&s_rnp1, np1_part[b * GX + tid]);
  }
  __syncthreads();

  if (tid == 0) {
    float tot = 0.f; unsigned pt = 0;
    for (int i = 0; i < 16; i++) { tot += wsum[i]; pt += wpt[i]; }
    if (fallback && C == R) tot += (float)(C - pt) * key2f(T);
    atomicAdd(&gacc->sc, tot);
    atomicAdd(&gacc->sl, s_rsl);
    atomicAdd(&gacc->slm, s_rslm);
    atomicAdd(&gacc->np, np);
    atomicAdd(&gacc->np1, s_rnp1);
  }
  __threadfence();
  __shared__ int lastF;
  if (tid == 0) lastF = (atomicAdd(&gacc->ticket, 1u) == (unsigned)(BN - 1)) ? 1 : 0;
  __syncthreads();
  if (lastF && tid == 0) {
    __threadfence();
    float sl = atomicAdd(&gacc->sl, 0.f);
    float slm = atomicAdd(&gacc->slm, 0.f);
    float sc = atomicAdd(&gacc->sc, 0.f);
    int tnp = atomicAdd(&gacc->np, 0);
    int tnp1 = atomicAdd(&gacc->np1, 0);
    float N = fmaxf((float)tnp, 1.f);
    float N1 = fmaxf((float)tnp1, 1.f);
    out[0] = sl / N;
    out[1] = sc / N;
    out[2] = slm / N1;
  }
}

extern "C" void kernel_launch(void* const* d_in, const int* in_sizes, int n_in,
                              void* d_out, int out_size, void* d_ws, size_t ws_size,
                              hipStream_t stream) {
  const float* loc_data = (const float*)d_in[0];
  const float* conf_data = (const float*)d_in[1];
  const float* landm_data = (const float*)d_in[2];
  const float* priors = (const float*)d_in[3];
  const float* targets = (const float*)d_in[4];
  float* out = (float*)d_out;

  char* ws = (char*)d_ws;
  const size_t SZ = (size_t)BN * PN * 4;
  size_t off = 0;
  float* lossc = (float*)(ws + off); off += SZ;
  float* bto = (float*)(ws + off); off += SZ;
  int* bti = (int*)(ws + off); off += SZ;
  unsigned char* posf = (unsigned char*)(ws + off); off += (size_t)BN * PN;
  off = (off + 15) & ~(size_t)15;
  unsigned long long* bpp = (unsigned long long*)(ws + off);
  off += (size_t)BN * ON * PSPLIT * 8;
  float* part_l = (float*)(ws + off); off += NBLK * 4;
  float* part_lm = (float*)(ws + off); off += NBLK * 4;
  int* np_part = (int*)(ws + off); off += NBLK * 4;
  int* np1_part = (int*)(ws + off); off += NBLK * 4;
  GAcc* gacc = (GAcc*)(ws + off); off += sizeof(GAcc);

  dim3 gbp(GX, BN);

  k_match2<<<NBT + NBP2, 256, 0, stream>>>(priors, targets, bto, bti, bpp, gacc);
  k_encode<<<gbp, 256, 0, stream>>>(loc_data, conf_data, landm_data, priors, targets,
                                    bto, bti, bpp, lossc, posf,
                                    part_l, part_lm, np_part, np1_part);
  k_select<<<BN, 1024, 0, stream>>>(lossc, posf, np_part, np1_part, part_l, part_lm,
                                    gacc, out);
}